// Round 1
// baseline (708.972 us; speedup 1.0000x reference)
//
#include <hip/hip_runtime.h>

// QuantumFeedForward: out = relu(cos(x[:,:8]) @ W1^T + b1) @ W2^T + b2
// x:[4,4096,1024] f32, W1:[4096,8], b1:[4096], W2:[1024,4096], b2:[1024]
// Strategy: bf16 MFMA for the dominant [16384,4096]x[4096,1024] GEMM.
//  K0: W2 f32->bf16 (8 MB)
//  K1: H[16384,4096] = relu(cos-dot) in bf16 (128 MB, memory-bound)
//  K2: m97-structure 128x128 GEMM, BK=32, 4 waves, global_load_lds(16B),
//      double-buffered LDS, 1 barrier/K-step, fp32 out + b2 epilogue.

#define EMBED 1024
#define FFN   4096
#define NQ    8
#define NTOK  16384        // 4*4096 tokens
#define NDIM  1024         // output embed (N)
#define KDIM  4096         // ffn (K)

#define BM 128
#define BN 128
#define BK 32
#define NKT (KDIM / BK)    // 128 K-steps

typedef __attribute__((ext_vector_type(8))) short short8;   // 8 bf16 = 4 VGPRs
typedef __attribute__((ext_vector_type(4))) float f32x4;

__device__ __forceinline__ unsigned short f2bf(float f) {
  // round-to-nearest-even f32 -> bf16 bits (no NaN care needed here)
  unsigned u = __float_as_uint(f);
  return (unsigned short)((u + 0x7FFFu + ((u >> 16) & 1u)) >> 16);
}

__device__ __forceinline__ void gload_lds16(const void* g, void* l) {
  __builtin_amdgcn_global_load_lds(
      (const __attribute__((address_space(1))) void*)g,
      (__attribute__((address_space(3))) void*)l, 16, 0, 0);
}

// ---- K0: W2 f32 -> bf16 ---------------------------------------------------
__global__ void w2cvt_kernel(const float* __restrict__ W2,
                             unsigned short* __restrict__ W2b) {
  const size_t idx = (size_t)blockIdx.x * blockDim.x + threadIdx.x; // covers 1M
  const float4 v = *reinterpret_cast<const float4*>(W2 + idx * 4);
  ushort4 o;
  o.x = f2bf(v.x); o.y = f2bf(v.y); o.z = f2bf(v.z); o.w = f2bf(v.w);
  *reinterpret_cast<ushort4*>(W2b + idx * 4) = o;
}

// ---- K1: H = relu(cos(x[:, :8]) @ W1^T + b1) in bf16 ----------------------
#define TOK 16
__global__ void h_kernel(const float* __restrict__ x,
                         const float* __restrict__ W1,
                         const float* __restrict__ b1,
                         unsigned short* __restrict__ H) {
  __shared__ float qs[TOK][NQ];
  const int tid = threadIdx.x;
  const int t0 = blockIdx.x * TOK;
  if (tid < TOK * NQ) {
    const int t = tid >> 3, q = tid & 7;
    qs[t][q] = __cosf(x[(size_t)(t0 + t) * EMBED + q]);
  }
  __syncthreads();
#pragma unroll 4
  for (int j = 0; j < FFN / 256; ++j) {
    const int f = j * 256 + tid;
    const float4 wa = *reinterpret_cast<const float4*>(W1 + (size_t)f * NQ);
    const float4 wb = *reinterpret_cast<const float4*>(W1 + (size_t)f * NQ + 4);
    const float bb = b1[f];
#pragma unroll
    for (int t = 0; t < TOK; ++t) {
      float h = fmaf(qs[t][0], wa.x, bb);
      h = fmaf(qs[t][1], wa.y, h);
      h = fmaf(qs[t][2], wa.z, h);
      h = fmaf(qs[t][3], wa.w, h);
      h = fmaf(qs[t][4], wb.x, h);
      h = fmaf(qs[t][5], wb.y, h);
      h = fmaf(qs[t][6], wb.z, h);
      h = fmaf(qs[t][7], wb.w, h);
      h = fmaxf(h, 0.0f);
      H[(size_t)(t0 + t) * FFN + f] = f2bf(h);
    }
  }
}

// ---- K2: out[M,N] = H[M,K] @ W2b[N,K]^T + b2 ------------------------------
__global__ __launch_bounds__(256) void gemm_kernel(
    const unsigned short* __restrict__ H,
    const unsigned short* __restrict__ W2b,
    const float* __restrict__ b2,
    float* __restrict__ out) {
  __shared__ unsigned short Ab[2][BM * BK];
  __shared__ unsigned short Bb[2][BM * BK];

  const int tid = threadIdx.x;
  const int bn = blockIdx.x;   // 0..7
  const int bm = blockIdx.y;   // 0..127
  const unsigned short* Abase = H   + (size_t)bm * BM * KDIM;
  const unsigned short* Bbase = W2b + (size_t)bn * BN * KDIM;

  const int lane = tid & 63;
  const int wid  = tid >> 6;   // 4 waves: 2x2 of 64x64 output
  const int wr   = wid >> 1;
  const int wc   = wid & 1;
  const int fr   = lane & 15;  // free index within 16x16 frag
  const int fq   = lane >> 4;  // k-subgroup
  const int koff = fq * 8;     // element offset in K within tile

  // staging: 512 chunks of 16B per 8KB tile; thread owns chunks tid, tid+256
  const int c0 = tid, c1 = 256 + tid;
  const int r0 = c0 >> 2, e0 = (c0 & 3) * 8;
  const int r1 = c1 >> 2, e1 = (c1 & 3) * 8;

  f32x4 acc[4][4];
#pragma unroll
  for (int m = 0; m < 4; ++m)
#pragma unroll
    for (int n = 0; n < 4; ++n) {
      f32x4 z = {0.0f, 0.0f, 0.0f, 0.0f};
      acc[m][n] = z;
    }

  // prologue: stage K-tile 0 into buf 0
  gload_lds16(Abase + (size_t)r0 * KDIM + e0, &Ab[0][c0 * 8]);
  gload_lds16(Abase + (size_t)r1 * KDIM + e1, &Ab[0][c1 * 8]);
  gload_lds16(Bbase + (size_t)r0 * KDIM + e0, &Bb[0][c0 * 8]);
  gload_lds16(Bbase + (size_t)r1 * KDIM + e1, &Bb[0][c1 * 8]);
  __syncthreads();   // drains vmcnt(0)

  int buf = 0;
  for (int kt = 0; kt < NKT; ++kt) {
    if (kt + 1 < NKT) {
      const size_t ko = (size_t)(kt + 1) * BK;
      gload_lds16(Abase + (size_t)r0 * KDIM + ko + e0, &Ab[buf ^ 1][c0 * 8]);
      gload_lds16(Abase + (size_t)r1 * KDIM + ko + e1, &Ab[buf ^ 1][c1 * 8]);
      gload_lds16(Bbase + (size_t)r0 * KDIM + ko + e0, &Bb[buf ^ 1][c0 * 8]);
      gload_lds16(Bbase + (size_t)r1 * KDIM + ko + e1, &Bb[buf ^ 1][c1 * 8]);
    }
    short8 af[4], bfrag[4];
#pragma unroll
    for (int m = 0; m < 4; ++m)
      af[m] = *reinterpret_cast<const short8*>(
          &Ab[buf][(wr * 64 + m * 16 + fr) * BK + koff]);
#pragma unroll
    for (int n = 0; n < 4; ++n)
      bfrag[n] = *reinterpret_cast<const short8*>(
          &Bb[buf][(wc * 64 + n * 16 + fr) * BK + koff]);
#pragma unroll
    for (int m = 0; m < 4; ++m)
#pragma unroll
      for (int n = 0; n < 4; ++n)
        acc[m][n] = __builtin_amdgcn_mfma_f32_16x16x32_bf16(
            af[m], bfrag[n], acc[m][n], 0, 0, 0);
    __syncthreads();  // drains staged loads (vmcnt) + my ds_reads (lgkm)
    buf ^= 1;
  }

  // epilogue: C/D layout col=lane&15, row=(lane>>4)*4+reg  [guide §3]
  const int orow0 = bm * BM + wr * 64 + fq * 4;
  const int ocol0 = bn * BN + wc * 64 + fr;
#pragma unroll
  for (int n = 0; n < 4; ++n) {
    const int col = ocol0 + n * 16;
    const float bias = b2[col];
#pragma unroll
    for (int m = 0; m < 4; ++m) {
      const int row = orow0 + m * 16;
#pragma unroll
      for (int r = 0; r < 4; ++r)
        out[(size_t)(row + r) * NDIM + col] = acc[m][n][r] + bias;
    }
  }
}

extern "C" void kernel_launch(void* const* d_in, const int* in_sizes, int n_in,
                              void* d_out, int out_size, void* d_ws, size_t ws_size,
                              hipStream_t stream) {
  const float* x  = (const float*)d_in[0];
  const float* W1 = (const float*)d_in[1];
  const float* b1 = (const float*)d_in[2];
  const float* W2 = (const float*)d_in[3];
  const float* b2 = (const float*)d_in[4];
  float* out = (float*)d_out;

  // workspace layout: H bf16 [16384*4096] (128 MB), W2 bf16 [1024*4096] (8 MB)
  unsigned short* H   = (unsigned short*)d_ws;
  unsigned short* W2b = (unsigned short*)((char*)d_ws + (size_t)NTOK * FFN * 2);

  hipLaunchKernelGGL(w2cvt_kernel, dim3((EMBED * KDIM / 4) / 256), dim3(256), 0,
                     stream, W2, W2b);
  hipLaunchKernelGGL(h_kernel, dim3(NTOK / TOK), dim3(256), 0, stream,
                     x, W1, b1, H);
  hipLaunchKernelGGL(gemm_kernel, dim3(NDIM / BN, NTOK / BM), dim3(256), 0,
                     stream, H, W2b, b2, out);
}

// Round 3
// 375.163 us; speedup vs baseline: 1.8898x; 1.8898x over previous
//
#include <hip/hip_runtime.h>

// QuantumFeedForward: out = relu(cos(x[:,:8]) @ W1^T + b1) @ W2^T + b2
// x:[4,4096,1024] f32, W1:[4096,8], b1:[4096], W2:[1024,4096], b2:[1024]
//  K0: W2 f32->bf16 (8 MB)
//  K1: H[16384,4096] = relu(cos-dot) bf16 — reg-resident W1, 16B stores
//  K2: m97-structure 128x128 GEMM (unchanged from R0)

#define EMBED 1024
#define FFN   4096
#define NQ    8
#define NTOK  16384        // 4*4096 tokens
#define NDIM  1024         // output embed (N)
#define KDIM  4096         // ffn (K)

#define BM 128
#define BN 128
#define BK 32
#define NKT (KDIM / BK)    // 128 K-steps

typedef __attribute__((ext_vector_type(8))) short short8;   // 8 bf16 = 4 VGPRs
typedef __attribute__((ext_vector_type(8))) unsigned short ushort8;
typedef __attribute__((ext_vector_type(4))) float f32x4;

__device__ __forceinline__ unsigned short f2bf(float f) {
  // round-to-nearest-even f32 -> bf16 bits
  unsigned u = __float_as_uint(f);
  return (unsigned short)((u + 0x7FFFu + ((u >> 16) & 1u)) >> 16);
}

__device__ __forceinline__ void gload_lds16(const void* g, void* l) {
  __builtin_amdgcn_global_load_lds(
      (const __attribute__((address_space(1))) void*)g,
      (__attribute__((address_space(3))) void*)l, 16, 0, 0);
}

// ---- K0: W2 f32 -> bf16 ---------------------------------------------------
__global__ void w2cvt_kernel(const float* __restrict__ W2,
                             unsigned short* __restrict__ W2b) {
  const size_t idx = (size_t)blockIdx.x * blockDim.x + threadIdx.x; // covers 1M
  const float4 v = *reinterpret_cast<const float4*>(W2 + idx * 4);
  ushort4 o;
  o.x = f2bf(v.x); o.y = f2bf(v.y); o.z = f2bf(v.z); o.w = f2bf(v.w);
  *reinterpret_cast<ushort4*>(W2b + idx * 4) = o;
}

// ---- K1: H = relu(cos(x[:, :8]) @ W1^T + b1) in bf16 ----------------------
// 512 threads: thread owns 8 consecutive f (W1 8x8 slice in VGPRs).
// Loop 64 tokens/block; q staged in LDS (broadcast); one 16B store/token.
#define TPB 64
__global__ __launch_bounds__(512) void h_kernel(
    const float* __restrict__ x,
    const float* __restrict__ W1,
    const float* __restrict__ b1,
    unsigned short* __restrict__ H) {
  __shared__ float q_lds[TPB][NQ];
  const int tid = threadIdx.x;
  const int t0 = blockIdx.x * TPB;

  if (tid < TPB) {
    const float4 a = *reinterpret_cast<const float4*>(
        x + (size_t)(t0 + tid) * EMBED);
    const float4 b = *reinterpret_cast<const float4*>(
        x + (size_t)(t0 + tid) * EMBED + 4);
    q_lds[tid][0] = __cosf(a.x); q_lds[tid][1] = __cosf(a.y);
    q_lds[tid][2] = __cosf(a.z); q_lds[tid][3] = __cosf(a.w);
    q_lds[tid][4] = __cosf(b.x); q_lds[tid][5] = __cosf(b.y);
    q_lds[tid][6] = __cosf(b.z); q_lds[tid][7] = __cosf(b.w);
  }

  // preload this thread's 8 W1 rows (256B contiguous) + 8 biases
  const int f8 = tid * 8;
  float w[8][8], bb[8];
#pragma unroll
  for (int j = 0; j < 8; ++j) {
    const float4 lo = *reinterpret_cast<const float4*>(W1 + (size_t)(f8 + j) * NQ);
    const float4 hi = *reinterpret_cast<const float4*>(W1 + (size_t)(f8 + j) * NQ + 4);
    w[j][0] = lo.x; w[j][1] = lo.y; w[j][2] = lo.z; w[j][3] = lo.w;
    w[j][4] = hi.x; w[j][5] = hi.y; w[j][6] = hi.z; w[j][7] = hi.w;
  }
  {
    const float4 lo = *reinterpret_cast<const float4*>(b1 + f8);
    const float4 hi = *reinterpret_cast<const float4*>(b1 + f8 + 4);
    bb[0] = lo.x; bb[1] = lo.y; bb[2] = lo.z; bb[3] = lo.w;
    bb[4] = hi.x; bb[5] = hi.y; bb[6] = hi.z; bb[7] = hi.w;
  }
  __syncthreads();

#pragma unroll 2
  for (int t = 0; t < TPB; ++t) {
    float q[8];
#pragma unroll
    for (int k = 0; k < NQ; ++k) q[k] = q_lds[t][k];  // broadcast reads
    ushort8 o;
#pragma unroll
    for (int j = 0; j < 8; ++j) {
      float h = bb[j];
#pragma unroll
      for (int k = 0; k < NQ; ++k) h = fmaf(q[k], w[j][k], h);
      h = fmaxf(h, 0.0f);
      o[j] = f2bf(h);
    }
    *reinterpret_cast<ushort8*>(H + (size_t)(t0 + t) * FFN + f8) = o;
  }
}

// ---- K2: out[M,N] = H[M,K] @ W2b[N,K]^T + b2 ------------------------------
__global__ __launch_bounds__(256) void gemm_kernel(
    const unsigned short* __restrict__ H,
    const unsigned short* __restrict__ W2b,
    const float* __restrict__ b2,
    float* __restrict__ out) {
  __shared__ unsigned short Ab[2][BM * BK];
  __shared__ unsigned short Bb[2][BM * BK];

  const int tid = threadIdx.x;
  const int bn = blockIdx.x;   // 0..7
  const int bm = blockIdx.y;   // 0..127
  const unsigned short* Abase = H   + (size_t)bm * BM * KDIM;
  const unsigned short* Bbase = W2b + (size_t)bn * BN * KDIM;

  const int lane = tid & 63;
  const int wid  = tid >> 6;   // 4 waves: 2x2 of 64x64 output
  const int wr   = wid >> 1;
  const int wc   = wid & 1;
  const int fr   = lane & 15;  // free index within 16x16 frag
  const int fq   = lane >> 4;  // k-subgroup
  const int koff = fq * 8;     // element offset in K within tile

  // staging: 512 chunks of 16B per 8KB tile; thread owns chunks tid, tid+256
  const int c0 = tid, c1 = 256 + tid;
  const int r0 = c0 >> 2, e0 = (c0 & 3) * 8;
  const int r1 = c1 >> 2, e1 = (c1 & 3) * 8;

  f32x4 acc[4][4];
#pragma unroll
  for (int m = 0; m < 4; ++m)
#pragma unroll
    for (int n = 0; n < 4; ++n) {
      f32x4 z = {0.0f, 0.0f, 0.0f, 0.0f};
      acc[m][n] = z;
    }

  // prologue: stage K-tile 0 into buf 0
  gload_lds16(Abase + (size_t)r0 * KDIM + e0, &Ab[0][c0 * 8]);
  gload_lds16(Abase + (size_t)r1 * KDIM + e1, &Ab[0][c1 * 8]);
  gload_lds16(Bbase + (size_t)r0 * KDIM + e0, &Bb[0][c0 * 8]);
  gload_lds16(Bbase + (size_t)r1 * KDIM + e1, &Bb[0][c1 * 8]);
  __syncthreads();   // drains vmcnt(0)

  int buf = 0;
  for (int kt = 0; kt < NKT; ++kt) {
    if (kt + 1 < NKT) {
      const size_t ko = (size_t)(kt + 1) * BK;
      gload_lds16(Abase + (size_t)r0 * KDIM + ko + e0, &Ab[buf ^ 1][c0 * 8]);
      gload_lds16(Abase + (size_t)r1 * KDIM + ko + e1, &Ab[buf ^ 1][c1 * 8]);
      gload_lds16(Bbase + (size_t)r0 * KDIM + ko + e0, &Bb[buf ^ 1][c0 * 8]);
      gload_lds16(Bbase + (size_t)r1 * KDIM + ko + e1, &Bb[buf ^ 1][c1 * 8]);
    }
    short8 af[4], bfrag[4];
#pragma unroll
    for (int m = 0; m < 4; ++m)
      af[m] = *reinterpret_cast<const short8*>(
          &Ab[buf][(wr * 64 + m * 16 + fr) * BK + koff]);
#pragma unroll
    for (int n = 0; n < 4; ++n)
      bfrag[n] = *reinterpret_cast<const short8*>(
          &Bb[buf][(wc * 64 + n * 16 + fr) * BK + koff]);
#pragma unroll
    for (int m = 0; m < 4; ++m)
#pragma unroll
      for (int n = 0; n < 4; ++n)
        acc[m][n] = __builtin_amdgcn_mfma_f32_16x16x32_bf16(
            af[m], bfrag[n], acc[m][n], 0, 0, 0);
    __syncthreads();  // drains staged loads (vmcnt) + my ds_reads (lgkm)
    buf ^= 1;
  }

  // epilogue: C/D layout col=lane&15, row=(lane>>4)*4+reg  [guide §3]
  const int orow0 = bm * BM + wr * 64 + fq * 4;
  const int ocol0 = bn * BN + wc * 64 + fr;
#pragma unroll
  for (int n = 0; n < 4; ++n) {
    const int col = ocol0 + n * 16;
    const float bias = b2[col];
#pragma unroll
    for (int m = 0; m < 4; ++m) {
      const int row = orow0 + m * 16;
#pragma unroll
      for (int r = 0; r < 4; ++r)
        out[(size_t)(row + r) * NDIM + col] = acc[m][n][r] + bias;
    }
  }
}

extern "C" void kernel_launch(void* const* d_in, const int* in_sizes, int n_in,
                              void* d_out, int out_size, void* d_ws, size_t ws_size,
                              hipStream_t stream) {
  const float* x  = (const float*)d_in[0];
  const float* W1 = (const float*)d_in[1];
  const float* b1 = (const float*)d_in[2];
  const float* W2 = (const float*)d_in[3];
  const float* b2 = (const float*)d_in[4];
  float* out = (float*)d_out;

  // workspace layout: H bf16 [16384*4096] (128 MB), W2 bf16 [1024*4096] (8 MB)
  unsigned short* H   = (unsigned short*)d_ws;
  unsigned short* W2b = (unsigned short*)((char*)d_ws + (size_t)NTOK * FFN * 2);

  hipLaunchKernelGGL(w2cvt_kernel, dim3((EMBED * KDIM / 4) / 256), dim3(256), 0,
                     stream, W2, W2b);
  hipLaunchKernelGGL(h_kernel, dim3(NTOK / TPB), dim3(512), 0, stream,
                     x, W1, b1, H);
  hipLaunchKernelGGL(gemm_kernel, dim3(NDIM / BN, NTOK / BM), dim3(256), 0,
                     stream, H, W2b, b2, out);
}

// Round 4
// 251.418 us; speedup vs baseline: 2.8199x; 1.4922x over previous
//
#include <hip/hip_runtime.h>

// QuantumFeedForward: out = relu(cos(x[:,:8]) @ W1^T + b1) @ W2^T + b2
//  K0: W2 f32->bf16
//  K1: H = relu(cos-dot) bf16 — reg-resident W1, coalesced q-load, 16B stores
//  K2: 256x256 GEMM, BK=32, 8 waves, triple-buffered LDS, counted vmcnt(4)
//      (never drains in main loop), XOR bank swizzle, XCD-chunked block swizzle.

#define EMBED 1024
#define FFN   4096
#define NQ    8
#define NTOK  16384        // 4*4096 tokens (M)
#define NDIM  1024         // output embed (N)
#define KDIM  4096         // ffn (K)

#define BM 256
#define BN 256
#define BK 32
#define NT (KDIM / BK)     // 128 K-tiles

typedef __attribute__((ext_vector_type(8))) short short8;   // 8 bf16 = 4 VGPRs
typedef __attribute__((ext_vector_type(8))) unsigned short ushort8;
typedef __attribute__((ext_vector_type(4))) float f32x4;

__device__ __forceinline__ unsigned short f2bf(float f) {
  unsigned u = __float_as_uint(f);
  return (unsigned short)((u + 0x7FFFu + ((u >> 16) & 1u)) >> 16);
}

__device__ __forceinline__ void gload_lds16(const void* g, void* l) {
  __builtin_amdgcn_global_load_lds(
      (const __attribute__((address_space(1))) void*)g,
      (__attribute__((address_space(3))) void*)l, 16, 0, 0);
}

// ---- K0: W2 f32 -> bf16 ---------------------------------------------------
__global__ void w2cvt_kernel(const float* __restrict__ W2,
                             unsigned short* __restrict__ W2b) {
  const size_t idx = (size_t)blockIdx.x * blockDim.x + threadIdx.x;
  const float4 v = *reinterpret_cast<const float4*>(W2 + idx * 4);
  ushort4 o;
  o.x = f2bf(v.x); o.y = f2bf(v.y); o.z = f2bf(v.z); o.w = f2bf(v.w);
  *reinterpret_cast<ushort4*>(W2b + idx * 4) = o;
}

// ---- K1: H = relu(cos(x[:, :8]) @ W1^T + b1) in bf16 ----------------------
#define TPB 64
__global__ __launch_bounds__(512) void h_kernel(
    const float* __restrict__ x,
    const float* __restrict__ W1,
    const float* __restrict__ b1,
    unsigned short* __restrict__ H) {
  __shared__ float q_lds[TPB][NQ];
  const int tid = threadIdx.x;
  const int t0 = blockIdx.x * TPB;

  if (tid < TPB * 2) {   // coalesced: 128 threads x float4
    const int t = tid >> 1, half = (tid & 1) * 4;
    const float4 v = *reinterpret_cast<const float4*>(
        x + (size_t)(t0 + t) * EMBED + half);
    q_lds[t][half + 0] = __cosf(v.x);
    q_lds[t][half + 1] = __cosf(v.y);
    q_lds[t][half + 2] = __cosf(v.z);
    q_lds[t][half + 3] = __cosf(v.w);
  }

  const int f8 = tid * 8;
  float w[8][8], bb[8];
#pragma unroll
  for (int j = 0; j < 8; ++j) {
    const float4 lo = *reinterpret_cast<const float4*>(W1 + (size_t)(f8 + j) * NQ);
    const float4 hi = *reinterpret_cast<const float4*>(W1 + (size_t)(f8 + j) * NQ + 4);
    w[j][0] = lo.x; w[j][1] = lo.y; w[j][2] = lo.z; w[j][3] = lo.w;
    w[j][4] = hi.x; w[j][5] = hi.y; w[j][6] = hi.z; w[j][7] = hi.w;
  }
  {
    const float4 lo = *reinterpret_cast<const float4*>(b1 + f8);
    const float4 hi = *reinterpret_cast<const float4*>(b1 + f8 + 4);
    bb[0] = lo.x; bb[1] = lo.y; bb[2] = lo.z; bb[3] = lo.w;
    bb[4] = hi.x; bb[5] = hi.y; bb[6] = hi.z; bb[7] = hi.w;
  }
  __syncthreads();

#pragma unroll 2
  for (int t = 0; t < TPB; ++t) {
    float q[8];
#pragma unroll
    for (int k = 0; k < NQ; ++k) q[k] = q_lds[t][k];
    ushort8 o;
#pragma unroll
    for (int j = 0; j < 8; ++j) {
      float h = bb[j];
#pragma unroll
      for (int k = 0; k < NQ; ++k) h = fmaf(q[k], w[j][k], h);
      h = fmaxf(h, 0.0f);
      o[j] = f2bf(h);
    }
    *reinterpret_cast<ushort8*>(H + (size_t)(t0 + t) * FFN + f8) = o;
  }
}

// ---- K2: out[M,N] = H[M,K] @ W2b[N,K]^T + b2 ------------------------------
// 256x256 tile, BK=32, 8 waves (2M x 4N), per-wave 128x64 output.
// Triple-buffered LDS: compute tile t from buf[t%3], stage tile t+2 into
// buf[(t+2)%3] (vacated at t-1). Counted vmcnt(4) per tile — loads issued
// this tile stay in flight across the barrier; never drains in main loop.
// LDS XOR swizzle: physical k-chunk = logical ^ ((row>>1)&3), applied on the
// global SOURCE address (linear gload_lds dest) and on the ds_read offset.
__global__ __launch_bounds__(512, 2) void gemm_kernel(
    const unsigned short* __restrict__ H,
    const unsigned short* __restrict__ W2b,
    const float* __restrict__ b2,
    float* __restrict__ out) {
  __shared__ unsigned short lds[3 * 2 * BM * BK];  // 3 bufs x (A,B) x 16KB = 96KB

  const int tid = threadIdx.x;
  // XCD-chunked bijective swizzle (256 wgs, 8 XCDs -> 32 contiguous per XCD)
  const int wg  = blockIdx.x;
  const int swz = (wg & 7) * 32 + (wg >> 3);
  const int bm  = swz >> 2;      // 0..63
  const int bn  = swz & 3;       // 0..3

  const unsigned short* Abase = H   + (size_t)bm * BM * KDIM;
  const unsigned short* Bbase = W2b + (size_t)bn * BN * KDIM;

  // staging: tile = 256 rows x 32 k (16KB) = 1024 16B-chunks; thread owns
  // chunks {tid, tid+512} of A and the same of B. chunk ch: row=ch>>2, c=ch&3.
  // source k-chunk = c ^ ((row>>1)&3)  (inverse swizzle; LDS dest linear)
  const int chA0 = tid, chA1 = tid + 512;
  const int rA0 = chA0 >> 2, cA0 = chA0 & 3;
  const int rA1 = chA1 >> 2, cA1 = chA1 & 3;
  const int src0 = rA0 * KDIM + (cA0 ^ ((rA0 >> 1) & 3)) * 8;
  const int src1 = rA1 * KDIM + (cA1 ^ ((rA1 >> 1) & 3)) * 8;
  const int d0 = chA0 * 8, d1 = chA1 * 8;

  const int lane = tid & 63;
  const int wid  = tid >> 6;     // 8 waves: wr in {0,1}, wc in {0..3}
  const int wr   = wid >> 2;
  const int wc   = wid & 3;
  const int fr   = lane & 15;
  const int fq   = lane >> 4;
  const int coff = (fq ^ ((fr >> 1) & 3)) * 8;  // swizzled k-chunk on read

  int offA[8], offB[4];
#pragma unroll
  for (int m = 0; m < 8; ++m) offA[m] = (wr * 128 + m * 16 + fr) * BK + coff;
#pragma unroll
  for (int n = 0; n < 4; ++n) offB[n] = (wc * 64 + n * 16 + fr) * BK + coff;

  f32x4 acc[8][4];
#pragma unroll
  for (int m = 0; m < 8; ++m)
#pragma unroll
    for (int n = 0; n < 4; ++n) {
      f32x4 z = {0.0f, 0.0f, 0.0f, 0.0f};
      acc[m][n] = z;
    }

  auto STAGE = [&](int t, int buf) {
    unsigned short* La = &lds[buf * (2 * BM * BK)];
    unsigned short* Lb = La + BM * BK;
    const size_t ko = (size_t)t * BK;
    gload_lds16(Abase + ko + src0, La + d0);
    gload_lds16(Abase + ko + src1, La + d1);
    gload_lds16(Bbase + ko + src0, Lb + d0);
    gload_lds16(Bbase + ko + src1, Lb + d1);
  };

  // prologue: tiles 0,1 staged; wait tile 0 only (tile 1 stays in flight)
  STAGE(0, 0);
  STAGE(1, 1);
  asm volatile("s_waitcnt vmcnt(4)" ::: "memory");
  __builtin_amdgcn_s_barrier();

  int bufc = 0;  // buffer holding tile t
  int bufs = 2;  // buffer receiving tile t+2
#pragma unroll 1
  for (int t = 0; t < NT; ++t) {
    if (t + 2 < NT) STAGE(t + 2, bufs);
    const unsigned short* La = &lds[bufc * (2 * BM * BK)];
    const unsigned short* Lb = La + BM * BK;
    short8 a[8], b[4];
#pragma unroll
    for (int m = 0; m < 8; ++m)
      a[m] = *reinterpret_cast<const short8*>(La + offA[m]);
#pragma unroll
    for (int n = 0; n < 4; ++n)
      b[n] = *reinterpret_cast<const short8*>(Lb + offB[n]);
    __builtin_amdgcn_s_setprio(1);
#pragma unroll
    for (int m = 0; m < 8; ++m)
#pragma unroll
      for (int n = 0; n < 4; ++n)
        acc[m][n] = __builtin_amdgcn_mfma_f32_16x16x32_bf16(
            a[m], b[n], acc[m][n], 0, 0, 0);
    __builtin_amdgcn_s_setprio(0);
    if (t < NT - 2) {
      // tile t+1's loads (issued at t-1) must be done; tile t+2's stay in flight
      asm volatile("s_waitcnt vmcnt(4)" ::: "memory");
      __builtin_amdgcn_s_barrier();
    } else if (t == NT - 2) {
      asm volatile("s_waitcnt vmcnt(0)" ::: "memory");
      __builtin_amdgcn_s_barrier();
    }
    bufc = (bufc == 2) ? 0 : bufc + 1;
    bufs = (bufs == 2) ? 0 : bufs + 1;
  }

  // epilogue: D element r -> row = m*16 + fq*4 + r, col = n*16 + fr (R1-verified)
  const int orow0 = bm * BM + wr * 128 + fq * 4;
  const int ocol0 = bn * BN + wc * 64 + fr;
#pragma unroll
  for (int n = 0; n < 4; ++n) {
    const int col = ocol0 + n * 16;
    const float bias = b2[col];
#pragma unroll
    for (int m = 0; m < 8; ++m) {
      const int row = orow0 + m * 16;
#pragma unroll
      for (int r = 0; r < 4; ++r)
        out[(size_t)(row + r) * NDIM + col] = acc[m][n][r] + bias;
    }
  }
}

extern "C" void kernel_launch(void* const* d_in, const int* in_sizes, int n_in,
                              void* d_out, int out_size, void* d_ws, size_t ws_size,
                              hipStream_t stream) {
  const float* x  = (const float*)d_in[0];
  const float* W1 = (const float*)d_in[1];
  const float* b1 = (const float*)d_in[2];
  const float* W2 = (const float*)d_in[3];
  const float* b2 = (const float*)d_in[4];
  float* out = (float*)d_out;

  unsigned short* Hb  = (unsigned short*)d_ws;
  unsigned short* W2b = (unsigned short*)((char*)d_ws + (size_t)NTOK * FFN * 2);

  hipLaunchKernelGGL(w2cvt_kernel, dim3((EMBED * KDIM / 4) / 256), dim3(256), 0,
                     stream, W2, W2b);
  hipLaunchKernelGGL(h_kernel, dim3(NTOK / TPB), dim3(512), 0, stream,
                     x, W1, b1, Hb);
  hipLaunchKernelGGL(gemm_kernel, dim3((NTOK / BM) * (NDIM / BN)), dim3(512), 0,
                     stream, Hb, W2b, b2, out);
}